// Round 1
// baseline (1358.165 us; speedup 1.0000x reference)
//
#include <hip/hip_runtime.h>

typedef unsigned short u16;
typedef __attribute__((ext_vector_type(8))) short bf16x8;
typedef __attribute__((ext_vector_type(4))) float f32x4;

#define C_    192
#define HW_   65536
#define NWIN  4096

__device__ inline u16 f2bf(float f) {
  union { float f; unsigned u; } x; x.f = f;
  unsigned r = x.u + 0x7FFFu + ((x.u >> 16) & 1u);
  return (u16)(r >> 16);
}
__device__ inline float bf2f(u16 s) {
  union { unsigned u; float f; } x; x.u = ((unsigned)s) << 16;
  return x.f;
}

// ---------------- k0: weight fp32 -> bf16 ----------------
__global__ void k_convert(const float* __restrict__ qkv_w,
                          const float* __restrict__ proj_w,
                          u16* __restrict__ wq, u16* __restrict__ wp) {
  int i = blockIdx.x * 256 + threadIdx.x;
  if (i < 110592) wq[i] = f2bf(qkv_w[i]);
  else            wp[i - 110592] = f2bf(proj_w[i - 110592]);
}

// ---------------- k1: CPB MLP table (225 x 8) ----------------
__global__ void k_table(const float* __restrict__ w1, const float* __restrict__ b1,
                        const float* __restrict__ w2, float* __restrict__ table) {
  int row = blockIdx.x;            // 0..224
  int tid = threadIdx.x;
  int a = row / 15, b = row % 15;
  float va = (float)(a - 7) * (8.0f / 7.0f);
  float vb = (float)(b - 7) * (8.0f / 7.0f);
  float c0 = copysignf(log2f(fabsf(va) + 1.0f) * (1.0f / 3.0f), va);
  float c1 = copysignf(log2f(fabsf(vb) + 1.0f) * (1.0f / 3.0f), vb);
  float acc[8];
#pragma unroll
  for (int o = 0; o < 8; ++o) acc[o] = 0.f;
  for (int k = tid; k < 512; k += 256) {
    float h = fmaxf(c0 * w1[k] + c1 * w1[512 + k] + b1[k], 0.f);
#pragma unroll
    for (int o = 0; o < 8; ++o) acc[o] += h * w2[k * 8 + o];
  }
  __shared__ float part[4][8];
  int wave = tid >> 6;
#pragma unroll
  for (int o = 0; o < 8; ++o) {
    float v = acc[o];
    v += __shfl_xor(v, 1, 64);  v += __shfl_xor(v, 2, 64);
    v += __shfl_xor(v, 4, 64);  v += __shfl_xor(v, 8, 64);
    v += __shfl_xor(v, 16, 64); v += __shfl_xor(v, 32, 64);
    acc[o] = v;
  }
  if ((tid & 63) == 0)
#pragma unroll
    for (int o = 0; o < 8; ++o) part[wave][o] = acc[o];
  __syncthreads();
  if (tid < 8)
    table[row * 8 + tid] = part[0][tid] + part[1][tid] + part[2][tid] + part[3][tid];
}

// ---------------- k2: full bias grid (8 x 64 x 64) ----------------
__global__ void k_biasfill(const float* __restrict__ table, float* __restrict__ biasf) {
  int p = blockIdx.x * 256 + threadIdx.x;   // 32768 total
  int h = p >> 12, t = (p >> 6) & 63, s = p & 63;
  int idx = ((t >> 3) - (s >> 3) + 7) * 15 + ((t & 7) - (s & 7) + 7);
  float v = table[idx * 8 + h];
  biasf[p] = 16.0f / (1.0f + __expf(-v));
}

// ---------------- main fused kernel: 1 window per block ----------------
__global__ __launch_bounds__(256, 1)
void k_main(const float* __restrict__ x,
            const float* __restrict__ q_bias, const float* __restrict__ v_bias,
            const float* __restrict__ ls, const float* __restrict__ proj_b,
            const u16* __restrict__ wq, const u16* __restrict__ wp,
            const float* __restrict__ biasf, float* __restrict__ out) {
  __shared__ u16 smem[78848];                 // 157,696 B
  u16* Xl = smem;                             // [64][200] bf16 : x window, later ao
  u16* qp = smem + 12800;                     // [8][64][40] bf16 (d 24..31 zero)
  u16* kp = smem + 33280;                     // [8][64][40]
  u16* vt = smem + 53760;                     // [8][32][72] v^T (d rows 24..31 zero)
  u16* Pl = smem + 72192;                     // [4][16][72] per-wave P bounce
  float* invq = (float*)(smem + 76800);       // [8][64]
  float* invk = invq + 512;                   // [8][64]
  float* obuf = (float*)(smem + 12800);       // [64][196] fp32, overlays qp/kp (proj phase)

  int tid  = threadIdx.x;
  int wave = tid >> 6, lane = tid & 63, g = lane >> 4, li = lane & 15;
  int bid = blockIdx.x;
  int b = bid >> 10, wy = (bid >> 5) & 31, wx = bid & 31;
  const float* xb = x + (size_t)b * C_ * HW_;
  int base = (wy * 8) * 256 + wx * 8;

  // ---- Phase 1: stage x window -> bf16 LDS; zero K/D pads ----
  for (int i4 = tid; i4 < 192 * 16; i4 += 256) {
    int c = i4 >> 4, rem = i4 & 15;
    int ty = rem >> 1, jj = (rem & 1) * 4;
    float4 v = *(const float4*)(xb + c * HW_ + base + ty * 256 + jj);
    int t = ty * 8 + jj;
    Xl[(t + 0) * 200 + c] = f2bf(v.x);
    Xl[(t + 1) * 200 + c] = f2bf(v.y);
    Xl[(t + 2) * 200 + c] = f2bf(v.z);
    Xl[(t + 3) * 200 + c] = f2bf(v.w);
  }
  for (int i = tid; i < 4096; i += 256) {     // q/k pad cols 24..31
    int h = i >> 9, rem = i & 511, t = rem >> 3, d = 24 + (rem & 7);
    qp[(h * 64 + t) * 40 + d] = 0;
    kp[(h * 64 + t) * 40 + d] = 0;
  }
  for (int i = tid; i < 4608; i += 256) {     // v^T pad rows d=24..31
    int h = i / 576, rem = i % 576, d = 24 + rem / 72, s = rem % 72;
    vt[(h * 32 + d) * 72 + s] = 0;
  }
  __syncthreads();

  // ---- Phase 2: QKV GEMM (wave = 16-token m-tile) ----
  {
    int mt = wave;
    bf16x8 af[6];
#pragma unroll
    for (int ks = 0; ks < 6; ++ks)
      af[ks] = *(const bf16x8*)&Xl[(mt * 16 + li) * 200 + ks * 32 + g * 8];
    for (int nt = 0; nt < 36; ++nt) {
      int j = nt * 16 + li;
      const u16* wr = wq + j * 192 + g * 8;
      f32x4 acc = {0.f, 0.f, 0.f, 0.f};
#pragma unroll
      for (int ks = 0; ks < 6; ++ks) {
        bf16x8 bfv = *(const bf16x8*)(wr + ks * 32);
        acc = __builtin_amdgcn_mfma_f32_16x16x32_bf16(af[ks], bfv, acc, 0, 0, 0);
      }
      float bias = (j < 192) ? q_bias[j] : ((j < 384) ? 0.f : v_bias[j - 384]);
      int which = j / 192, jm = j % 192, h = jm / 24, d = jm % 24;
#pragma unroll
      for (int r = 0; r < 4; ++r) {
        int t = mt * 16 + g * 4 + r;
        u16 bv = f2bf(acc[r] + bias);
        if (which == 0)      qp[(h * 64 + t) * 40 + d] = bv;
        else if (which == 1) kp[(h * 64 + t) * 40 + d] = bv;
        else                 vt[(h * 32 + d) * 72 + t] = bv;
      }
    }
  }
  __syncthreads();

  // ---- Phase 3: inverse norms of q,k per (head, token) ----
  for (int i = 0; i < 4; ++i) {
    int p = tid + i * 256;                    // 1024 tasks
    int tensor = p >> 9, h = (p >> 6) & 7, t = p & 63;
    const u16* row = (tensor == 0 ? qp : kp) + (h * 64 + t) * 40;
    const bf16x8* r8 = (const bf16x8*)row;
    float ssq = 0.f;
#pragma unroll
    for (int ch = 0; ch < 3; ++ch) {
      bf16x8 v8 = r8[ch];
#pragma unroll
      for (int e = 0; e < 8; ++e) { float v = bf2f((u16)v8[e]); ssq += v * v; }
    }
    float inv = 1.0f / fmaxf(sqrtf(ssq), 1e-12f);
    (tensor == 0 ? invq : invk)[h * 64 + t] = inv;
  }
  __syncthreads();

  // ---- Phase 4: attention; wave handles heads {wave, wave+4} ----
  for (int hh = 0; hh < 2; ++hh) {
    int h = wave + hh * 4;
    float sc = __expf(fminf(ls[h], 4.6051702f));   // exp(min(ls, ln 100))
    bf16x8 vf[2][2];
#pragma unroll
    for (int md = 0; md < 2; ++md)
#pragma unroll
      for (int ks = 0; ks < 2; ++ks)
        vf[md][ks] = *(const bf16x8*)&vt[(h * 32 + md * 16 + li) * 72 + ks * 32 + g * 8];
    u16* Pw = Pl + wave * (16 * 72);
    for (int tb = 0; tb < 4; ++tb) {
      bf16x8 qf = *(const bf16x8*)&qp[(h * 64 + tb * 16 + li) * 40 + g * 8];
      f32x4 s4[4];
#pragma unroll
      for (int nt = 0; nt < 4; ++nt) {
        bf16x8 kf = *(const bf16x8*)&kp[(h * 64 + nt * 16 + li) * 40 + g * 8];
        f32x4 z = {0.f, 0.f, 0.f, 0.f};
        s4[nt] = __builtin_amdgcn_mfma_f32_16x16x32_bf16(qf, kf, z, 0, 0, 0);
      }
      const float* bp = biasf + ((h * 64 + tb * 16 + g * 4) * 64) + li;
      float iq[4];
#pragma unroll
      for (int r = 0; r < 4; ++r) iq[r] = invq[h * 64 + tb * 16 + g * 4 + r] * sc;
#pragma unroll
      for (int nt = 0; nt < 4; ++nt) {
        float ik = invk[h * 64 + nt * 16 + li];
#pragma unroll
        for (int r = 0; r < 4; ++r)
          s4[nt][r] = s4[nt][r] * iq[r] * ik + bp[r * 64 + nt * 16];
      }
#pragma unroll
      for (int r = 0; r < 4; ++r) {           // softmax over s (row = token)
        float m = fmaxf(fmaxf(s4[0][r], s4[1][r]), fmaxf(s4[2][r], s4[3][r]));
        m = fmaxf(m, __shfl_xor(m, 1, 64));
        m = fmaxf(m, __shfl_xor(m, 2, 64));
        m = fmaxf(m, __shfl_xor(m, 4, 64));
        m = fmaxf(m, __shfl_xor(m, 8, 64));
        float sum = 0.f;
#pragma unroll
        for (int nt = 0; nt < 4; ++nt) { float e = __expf(s4[nt][r] - m); s4[nt][r] = e; sum += e; }
        sum += __shfl_xor(sum, 1, 64);
        sum += __shfl_xor(sum, 2, 64);
        sum += __shfl_xor(sum, 4, 64);
        sum += __shfl_xor(sum, 8, 64);
        float is = 1.0f / sum;
#pragma unroll
        for (int nt = 0; nt < 4; ++nt)
          Pw[(g * 4 + r) * 72 + nt * 16 + li] = f2bf(s4[nt][r] * is);
      }
      // PV: O^T = V^T * P^T  (same-wave LDS bounce; DS is in-order per wave)
      f32x4 o0 = {0.f, 0.f, 0.f, 0.f}, o1 = o0;
#pragma unroll
      for (int ks = 0; ks < 2; ++ks) {
        bf16x8 pf = *(const bf16x8*)&Pw[li * 72 + ks * 32 + g * 8];
        o0 = __builtin_amdgcn_mfma_f32_16x16x32_bf16(vf[0][ks], pf, o0, 0, 0, 0);
        o1 = __builtin_amdgcn_mfma_f32_16x16x32_bf16(vf[1][ks], pf, o1, 0, 0, 0);
      }
      int t = tb * 16 + li;
#pragma unroll
      for (int r = 0; r < 4; ++r) {
        int d0 = g * 4 + r;
        Xl[t * 200 + h * 24 + d0] = f2bf(o0[r]);       // d0 < 16 always
        int d1 = 16 + g * 4 + r;
        if (d1 < 24) Xl[t * 200 + h * 24 + d1] = f2bf(o1[r]);
      }
    }
  }
  __syncthreads();

  // ---- Phase 5: proj GEMM (wave = m-tile), into fp32 LDS ----
  {
    int mt = wave;
    bf16x8 af[6];
#pragma unroll
    for (int ks = 0; ks < 6; ++ks)
      af[ks] = *(const bf16x8*)&Xl[(mt * 16 + li) * 200 + ks * 32 + g * 8];
    for (int nt = 0; nt < 12; ++nt) {
      const u16* wr = wp + (nt * 16 + li) * 192 + g * 8;
      f32x4 acc = {0.f, 0.f, 0.f, 0.f};
#pragma unroll
      for (int ks = 0; ks < 6; ++ks) {
        bf16x8 bfv = *(const bf16x8*)(wr + ks * 32);
        acc = __builtin_amdgcn_mfma_f32_16x16x32_bf16(af[ks], bfv, acc, 0, 0, 0);
      }
      int c = nt * 16 + li;
      float pb = proj_b[c];
#pragma unroll
      for (int r = 0; r < 4; ++r)
        obuf[(mt * 16 + g * 4 + r) * 196 + c] = acc[r] + pb;
    }
  }
  __syncthreads();

  // ---- Phase 6: residual + coalesced store ----
  float* ob = out + (size_t)b * C_ * HW_;
  for (int i4 = tid; i4 < 192 * 16; i4 += 256) {
    int c = i4 >> 4, rem = i4 & 15;
    int ty = rem >> 1, jj = (rem & 1) * 4;
    int off = c * HW_ + base + ty * 256 + jj;
    float4 xv = *(const float4*)(xb + off);
    int t = ty * 8 + jj;
    float4 r;
    r.x = xv.x + obuf[(t + 0) * 196 + c];
    r.y = xv.y + obuf[(t + 1) * 196 + c];
    r.z = xv.z + obuf[(t + 2) * 196 + c];
    r.w = xv.w + obuf[(t + 3) * 196 + c];
    *(float4*)(ob + off) = r;
  }
}

// ---------------- launcher ----------------
extern "C" void kernel_launch(void* const* d_in, const int* in_sizes, int n_in,
                              void* d_out, int out_size, void* d_ws, size_t ws_size,
                              hipStream_t stream) {
  const float* x      = (const float*)d_in[0];
  // d_in[1] = img_alpha (no-op for shift_size==0)
  const float* qkv_w  = (const float*)d_in[2];
  const float* q_bias = (const float*)d_in[3];
  const float* v_bias = (const float*)d_in[4];
  const float* ls     = (const float*)d_in[5];
  const float* w1     = (const float*)d_in[6];
  const float* b1     = (const float*)d_in[7];
  const float* w2     = (const float*)d_in[8];
  const float* proj_w = (const float*)d_in[9];
  const float* proj_b = (const float*)d_in[10];

  u16*   wq    = (u16*)d_ws;                               // 110592 bf16
  u16*   wpv   = wq + 110592;                              // 36864 bf16
  float* biasf = (float*)((char*)d_ws + 294912);           // 32768 f32
  float* table = (float*)((char*)d_ws + 425984);           // 1800 f32
  float* out   = (float*)d_out;

  hipLaunchKernelGGL(k_convert, dim3(576), dim3(256), 0, stream, qkv_w, proj_w, wq, wpv);
  hipLaunchKernelGGL(k_table, dim3(225), dim3(256), 0, stream, w1, b1, w2, table);
  hipLaunchKernelGGL(k_biasfill, dim3(128), dim3(256), 0, stream, table, biasf);
  hipLaunchKernelGGL(k_main, dim3(NWIN), dim3(256), 0, stream,
                     x, q_bias, v_bias, ls, proj_b, wq, wpv, biasf, out);
}

// Round 2
// 832.991 us; speedup vs baseline: 1.6305x; 1.6305x over previous
//
#include <hip/hip_runtime.h>

typedef unsigned short u16;
typedef __attribute__((ext_vector_type(8))) short bf16x8;
typedef __attribute__((ext_vector_type(4))) float f32x4;

#define C_    192
#define HW_   65536
#define NWIN  4096

__device__ inline u16 f2bf(float f) {
  union { float f; unsigned u; } x; x.f = f;
  unsigned r = x.u + 0x7FFFu + ((x.u >> 16) & 1u);
  return (u16)(r >> 16);
}
__device__ inline float bf2f(u16 s) {
  union { unsigned u; float f; } x; x.u = ((unsigned)s) << 16;
  return x.f;
}

// ---------------- k0: weights fp32 -> bf16, combined qkv bias ----------------
__global__ void k_convert(const float* __restrict__ qkv_w, const float* __restrict__ proj_w,
                          const float* __restrict__ q_bias, const float* __restrict__ v_bias,
                          u16* __restrict__ wq, u16* __restrict__ wp, float* __restrict__ qkvb) {
  int i = blockIdx.x * 256 + threadIdx.x;
  if (i < 110592) wq[i] = f2bf(qkv_w[i]);
  else if (i < 147456) wp[i - 110592] = f2bf(proj_w[i - 110592]);
  else if (i < 148032) {
    int j = i - 147456;
    qkvb[j] = (j < 192) ? q_bias[j] : ((j < 384) ? 0.f : v_bias[j - 384]);
  }
}

// ---------------- k1: CPB MLP table (225 x 8) ----------------
__global__ void k_table(const float* __restrict__ w1, const float* __restrict__ b1,
                        const float* __restrict__ w2, float* __restrict__ table) {
  int row = blockIdx.x;            // 0..224
  int tid = threadIdx.x;
  int a = row / 15, b = row % 15;
  float va = (float)(a - 7) * (8.0f / 7.0f);
  float vb = (float)(b - 7) * (8.0f / 7.0f);
  float c0 = copysignf(log2f(fabsf(va) + 1.0f) * (1.0f / 3.0f), va);
  float c1 = copysignf(log2f(fabsf(vb) + 1.0f) * (1.0f / 3.0f), vb);
  float acc[8];
#pragma unroll
  for (int o = 0; o < 8; ++o) acc[o] = 0.f;
  for (int k = tid; k < 512; k += 256) {
    float h = fmaxf(c0 * w1[k] + c1 * w1[512 + k] + b1[k], 0.f);
#pragma unroll
    for (int o = 0; o < 8; ++o) acc[o] += h * w2[k * 8 + o];
  }
  __shared__ float part[4][8];
  int wave = tid >> 6;
#pragma unroll
  for (int o = 0; o < 8; ++o) {
    float v = acc[o];
    v += __shfl_xor(v, 1, 64);  v += __shfl_xor(v, 2, 64);
    v += __shfl_xor(v, 4, 64);  v += __shfl_xor(v, 8, 64);
    v += __shfl_xor(v, 16, 64); v += __shfl_xor(v, 32, 64);
    acc[o] = v;
  }
  if ((tid & 63) == 0)
#pragma unroll
    for (int o = 0; o < 8; ++o) part[wave][o] = acc[o];
  __syncthreads();
  if (tid < 8)
    table[row * 8 + tid] = part[0][tid] + part[1][tid] + part[2][tid] + part[3][tid];
}

// ---------------- k2: bias grid, permuted [h][tb][lane][r*4+nt] ----------------
__global__ void k_biasfill(const float* __restrict__ table, float* __restrict__ bias2) {
  int p = blockIdx.x * 256 + threadIdx.x;   // 32768 total
  int h = p >> 12, tb = (p >> 10) & 3, lane = (p >> 4) & 63, u = p & 15;
  int r = u >> 2, nt = u & 3, g = lane >> 4, li = lane & 15;
  int t = tb * 16 + g * 4 + r, s = nt * 16 + li;
  int idx = ((t >> 3) - (s >> 3) + 7) * 15 + ((t & 7) - (s & 7) + 7);
  float v = table[idx * 8 + h];
  bias2[p] = 16.0f / (1.0f + __expf(-v));
}

// ---------------- main fused kernel: 1 window per block, 8 waves ----------------
__global__ __launch_bounds__(512, 2)
void k_main(const float* __restrict__ x,
            const float* __restrict__ ls, const float* __restrict__ proj_b,
            const u16* __restrict__ wq, const u16* __restrict__ wp,
            const float* __restrict__ qkvb, const float* __restrict__ bias2,
            float* __restrict__ out) {
  __shared__ u16 smem[63488];                 // 126,976 B
  u16* XQ = smem;                             // [64][200]: x window, then q
  u16* Kl = smem + 12800;                     // [64][200]: k
  u16* vt = smem + 25600;                     // [192][72]: v^T rows = h*24+d
  u16* ao = smem + 39424;                     // [64][200]: attention out (bf16)
  u16* Pl = smem + 52224;                     // 8 x [16][72] per-wave P bounce
  float* invq = (float*)(smem + 61440);       // [8][64] (has logit scale folded)
  float* invk = (float*)(smem + 62464);       // [8][64]
  float* obuf = (float*)smem;                 // [64][197] fp32, overlays XQ+Kl

  int tid  = threadIdx.x;
  int wave = tid >> 6, lane = tid & 63, g = lane >> 4, li = lane & 15;
  int bid = blockIdx.x;
  int b = bid >> 10, wy = (bid >> 5) & 31, wx = bid & 31;
  const float* xb = x + (size_t)b * C_ * HW_;
  int base = (wy * 8) * 256 + wx * 8;

  // ---- P1: stage x -> bf16 LDS; keep fp32 in regs for residual ----
  float4 xr[6];
#pragma unroll
  for (int it = 0; it < 6; ++it) {
    int i4 = tid + it * 512;                  // 3072 tasks
    int c = i4 >> 4, rem = i4 & 15;
    int ty = rem >> 1, jj = (rem & 1) * 4;
    xr[it] = *(const float4*)(xb + c * HW_ + base + ty * 256 + jj);
    int t = ty * 8 + jj;
    XQ[(t + 0) * 200 + c] = f2bf(xr[it].x);
    XQ[(t + 1) * 200 + c] = f2bf(xr[it].y);
    XQ[(t + 2) * 200 + c] = f2bf(xr[it].z);
    XQ[(t + 3) * 200 + c] = f2bf(xr[it].w);
  }
  __syncthreads();                            // B1

  // ---- P2: QKV GEMM; wave = (mt, n-half) ----
  {
    int mt = wave & 3, nb = (wave >> 2) * 18;
    bf16x8 af[6];
#pragma unroll
    for (int ks = 0; ks < 6; ++ks)
      af[ks] = *(const bf16x8*)&XQ[(mt * 16 + li) * 200 + ks * 32 + g * 8];
    __syncthreads();                          // B2: all A-frags in regs; q may overwrite XQ
#pragma unroll
    for (int it = 0; it < 18; ++it) {
      int nt = nb + it;
      int j = nt * 16 + li;
      const u16* wr = wq + j * 192 + g * 8;
      f32x4 acc = {0.f, 0.f, 0.f, 0.f};
#pragma unroll
      for (int ks = 0; ks < 6; ++ks) {
        bf16x8 bfv = *(const bf16x8*)(wr + ks * 32);
        acc = __builtin_amdgcn_mfma_f32_16x16x32_bf16(af[ks], bfv, acc, 0, 0, 0);
      }
      float cb = qkvb[j];
      if (j < 384) {                          // q or k: [t][c] scatter
        u16* dst = (j < 192) ? XQ : Kl;
        int col = (j < 192) ? j : j - 192;
#pragma unroll
        for (int r = 0; r < 4; ++r)
          dst[(mt * 16 + g * 4 + r) * 200 + col] = f2bf(acc[r] + cb);
      } else {                                // v: packed b64 into v^T
        int row = j - 384;                    // = h*24+d
        unsigned p0 = f2bf(acc[0] + cb) | ((unsigned)f2bf(acc[1] + cb) << 16);
        unsigned p1 = f2bf(acc[2] + cb) | ((unsigned)f2bf(acc[3] + cb) << 16);
        uint2 pk; pk.x = p0; pk.y = p1;
        *(uint2*)&vt[row * 72 + mt * 16 + g * 4] = pk;
      }
    }
  }
  __syncthreads();                            // B3

  // ---- P3: inverse norms (logit scale folded into invq) ----
#pragma unroll
  for (int i = 0; i < 2; ++i) {
    int p = tid + i * 512;                    // 1024 tasks
    int tensor = p >> 9, h = (p >> 6) & 7, t = p & 63;
    const u16* row = (tensor == 0 ? XQ : Kl) + t * 200 + h * 24;
    const bf16x8* r8 = (const bf16x8*)row;
    float ssq = 0.f;
#pragma unroll
    for (int ch = 0; ch < 3; ++ch) {
      bf16x8 v8 = r8[ch];
#pragma unroll
      for (int e = 0; e < 8; ++e) { float v = bf2f((u16)v8[e]); ssq += v * v; }
    }
    float inv = __builtin_amdgcn_rsqf(fmaxf(ssq, 1e-24f));
    if (tensor == 0) {
      inv *= __expf(fminf(ls[h], 4.6051702f));
      invq[h * 64 + t] = inv;
    } else invk[h * 64 + t] = inv;
  }
  __syncthreads();                            // B4

  // ---- P4: attention; wave = head ----
  {
    int h = wave;
    bf16x8 z8 = {0, 0, 0, 0, 0, 0, 0, 0};
    bf16x8 vf0[2], vf1[2];
#pragma unroll
    for (int ks = 0; ks < 2; ++ks) {
      vf0[ks] = *(const bf16x8*)&vt[(h * 24 + li) * 72 + ks * 32 + g * 8];
      vf1[ks] = (li < 8) ? *(const bf16x8*)&vt[(h * 24 + 16 + li) * 72 + ks * 32 + g * 8] : z8;
    }
    u16* Pw = Pl + wave * 1152;
#pragma unroll
    for (int tb = 0; tb < 4; ++tb) {
      const f32x4* bp = (const f32x4*)(bias2 + (((h * 4 + tb) * 64 + lane) << 4));
      f32x4 bx[4];
#pragma unroll
      for (int r = 0; r < 4; ++r) bx[r] = bp[r];
      bf16x8 qf = (g < 3) ? *(const bf16x8*)&XQ[(tb * 16 + li) * 200 + h * 24 + g * 8] : z8;
      f32x4 s4[4];
#pragma unroll
      for (int nt = 0; nt < 4; ++nt) {
        bf16x8 kf = (g < 3) ? *(const bf16x8*)&Kl[(nt * 16 + li) * 200 + h * 24 + g * 8] : z8;
        f32x4 z = {0.f, 0.f, 0.f, 0.f};
        s4[nt] = __builtin_amdgcn_mfma_f32_16x16x32_bf16(qf, kf, z, 0, 0, 0);
      }
      f32x4 iq = ((const f32x4*)(invq + h * 64 + tb * 16))[g];
#pragma unroll
      for (int nt = 0; nt < 4; ++nt) {
        float ik = invk[h * 64 + nt * 16 + li];
#pragma unroll
        for (int r = 0; r < 4; ++r)
          s4[nt][r] = s4[nt][r] * iq[r] * ik + bx[r][nt];
      }
#pragma unroll
      for (int r = 0; r < 4; ++r) {
        float m = fmaxf(fmaxf(s4[0][r], s4[1][r]), fmaxf(s4[2][r], s4[3][r]));
        m = fmaxf(m, __shfl_xor(m, 1, 64));
        m = fmaxf(m, __shfl_xor(m, 2, 64));
        m = fmaxf(m, __shfl_xor(m, 4, 64));
        m = fmaxf(m, __shfl_xor(m, 8, 64));
        float sum = 0.f;
#pragma unroll
        for (int nt = 0; nt < 4; ++nt) { float e = __expf(s4[nt][r] - m); s4[nt][r] = e; sum += e; }
        sum += __shfl_xor(sum, 1, 64);
        sum += __shfl_xor(sum, 2, 64);
        sum += __shfl_xor(sum, 4, 64);
        sum += __shfl_xor(sum, 8, 64);
        float is = __builtin_amdgcn_rcpf(sum);
#pragma unroll
        for (int nt = 0; nt < 4; ++nt)
          Pw[(g * 4 + r) * 72 + nt * 16 + li] = f2bf(s4[nt][r] * is);
      }
      // PV: O^T = V^T * P^T (same-wave LDS bounce)
      f32x4 o0 = {0.f, 0.f, 0.f, 0.f}, o1 = o0;
#pragma unroll
      for (int ks = 0; ks < 2; ++ks) {
        bf16x8 pf = *(const bf16x8*)&Pw[li * 72 + ks * 32 + g * 8];
        o0 = __builtin_amdgcn_mfma_f32_16x16x32_bf16(vf0[ks], pf, o0, 0, 0, 0);
        o1 = __builtin_amdgcn_mfma_f32_16x16x32_bf16(vf1[ks], pf, o1, 0, 0, 0);
      }
      int t = tb * 16 + li;
      {
        uint2 pk;
        pk.x = f2bf(o0[0]) | ((unsigned)f2bf(o0[1]) << 16);
        pk.y = f2bf(o0[2]) | ((unsigned)f2bf(o0[3]) << 16);
        *(uint2*)&ao[t * 200 + h * 24 + g * 4] = pk;           // d = g*4..g*4+3
      }
      if (g < 2) {
        uint2 pk;
        pk.x = f2bf(o1[0]) | ((unsigned)f2bf(o1[1]) << 16);
        pk.y = f2bf(o1[2]) | ((unsigned)f2bf(o1[3]) << 16);
        *(uint2*)&ao[t * 200 + h * 24 + 16 + g * 4] = pk;      // d = 16+g*4..
      }
    }
  }
  __syncthreads();                            // B5 (XQ/Kl now dead -> obuf)

  // ---- P5: proj GEMM; wave = (mt, n-half) ----
  {
    int mt = wave & 3, nb2 = (wave >> 2) * 6;
    bf16x8 af[6];
#pragma unroll
    for (int ks = 0; ks < 6; ++ks)
      af[ks] = *(const bf16x8*)&ao[(mt * 16 + li) * 200 + ks * 32 + g * 8];
#pragma unroll
    for (int it = 0; it < 6; ++it) {
      int nt = nb2 + it;
      const u16* wr = wp + (nt * 16 + li) * 192 + g * 8;
      f32x4 acc = {0.f, 0.f, 0.f, 0.f};
#pragma unroll
      for (int ks = 0; ks < 6; ++ks) {
        bf16x8 bfv = *(const bf16x8*)(wr + ks * 32);
        acc = __builtin_amdgcn_mfma_f32_16x16x32_bf16(af[ks], bfv, acc, 0, 0, 0);
      }
      float pb = proj_b[nt * 16 + li];
#pragma unroll
      for (int r = 0; r < 4; ++r)
        obuf[(mt * 16 + g * 4 + r) * 197 + nt * 16 + li] = acc[r] + pb;
    }
  }
  __syncthreads();                            // B6

  // ---- P6: residual from regs + coalesced store ----
  float* ob = out + (size_t)b * C_ * HW_;
#pragma unroll
  for (int it = 0; it < 6; ++it) {
    int i4 = tid + it * 512;
    int c = i4 >> 4, rem = i4 & 15;
    int ty = rem >> 1, jj = (rem & 1) * 4;
    int t = ty * 8 + jj;
    float4 r;
    r.x = xr[it].x + obuf[(t + 0) * 197 + c];
    r.y = xr[it].y + obuf[(t + 1) * 197 + c];
    r.z = xr[it].z + obuf[(t + 2) * 197 + c];
    r.w = xr[it].w + obuf[(t + 3) * 197 + c];
    *(float4*)(ob + c * HW_ + base + ty * 256 + jj) = r;
  }
}

// ---------------- launcher ----------------
extern "C" void kernel_launch(void* const* d_in, const int* in_sizes, int n_in,
                              void* d_out, int out_size, void* d_ws, size_t ws_size,
                              hipStream_t stream) {
  const float* x      = (const float*)d_in[0];
  const float* qkv_w  = (const float*)d_in[2];
  const float* q_bias = (const float*)d_in[3];
  const float* v_bias = (const float*)d_in[4];
  const float* ls     = (const float*)d_in[5];
  const float* w1     = (const float*)d_in[6];
  const float* b1     = (const float*)d_in[7];
  const float* w2     = (const float*)d_in[8];
  const float* proj_w = (const float*)d_in[9];
  const float* proj_b = (const float*)d_in[10];

  u16*   wq    = (u16*)d_ws;                               // 110592 bf16
  u16*   wpv   = wq + 110592;                              // 36864 bf16 -> ends at byte 294912
  float* qkvb  = (float*)((char*)d_ws + 294912);           // 576 f32   -> 297216
  float* bias2 = (float*)((char*)d_ws + 297216);           // 32768 f32 -> 428288
  float* table = (float*)((char*)d_ws + 428288);           // 1800 f32
  float* out   = (float*)d_out;

  hipLaunchKernelGGL(k_convert, dim3(579), dim3(256), 0, stream,
                     qkv_w, proj_w, q_bias, v_bias, wq, wpv, qkvb);
  hipLaunchKernelGGL(k_table, dim3(225), dim3(256), 0, stream, w1, b1, w2, table);
  hipLaunchKernelGGL(k_biasfill, dim3(128), dim3(256), 0, stream, table, bias2);
  hipLaunchKernelGGL(k_main, dim3(NWIN), dim3(512), 0, stream,
                     x, ls, proj_b, wq, wpv, qkvb, bias2, out);
}

// Round 3
// 756.230 us; speedup vs baseline: 1.7960x; 1.1015x over previous
//
#include <hip/hip_runtime.h>

typedef unsigned short u16;
typedef __attribute__((ext_vector_type(8))) short bf16x8;
typedef __attribute__((ext_vector_type(4))) float f32x4;

#define C_    192
#define HW_   65536
#define NWIN  4096

__device__ inline u16 f2bf(float f) {
  union { float f; unsigned u; } x; x.f = f;
  unsigned r = x.u + 0x7FFFu + ((x.u >> 16) & 1u);
  return (u16)(r >> 16);
}
__device__ inline float bf2f(u16 s) {
  union { unsigned u; float f; } x; x.u = ((unsigned)s) << 16;
  return x.f;
}

// ---------------- k0: weights fp32 -> bf16, combined qkv bias ----------------
__global__ void k_convert(const float* __restrict__ qkv_w, const float* __restrict__ proj_w,
                          const float* __restrict__ q_bias, const float* __restrict__ v_bias,
                          u16* __restrict__ wq, u16* __restrict__ wp, float* __restrict__ qkvb) {
  int i = blockIdx.x * 256 + threadIdx.x;
  if (i < 110592) wq[i] = f2bf(qkv_w[i]);
  else if (i < 147456) wp[i - 110592] = f2bf(proj_w[i - 110592]);
  else if (i < 148032) {
    int j = i - 147456;
    qkvb[j] = (j < 192) ? q_bias[j] : ((j < 384) ? 0.f : v_bias[j - 384]);
  }
}

// ---------------- k1: CPB MLP table (225 x 8) ----------------
__global__ void k_table(const float* __restrict__ w1, const float* __restrict__ b1,
                        const float* __restrict__ w2, float* __restrict__ table) {
  int row = blockIdx.x;            // 0..224
  int tid = threadIdx.x;
  int a = row / 15, b = row % 15;
  float va = (float)(a - 7) * (8.0f / 7.0f);
  float vb = (float)(b - 7) * (8.0f / 7.0f);
  float c0 = copysignf(log2f(fabsf(va) + 1.0f) * (1.0f / 3.0f), va);
  float c1 = copysignf(log2f(fabsf(vb) + 1.0f) * (1.0f / 3.0f), vb);
  float acc[8];
#pragma unroll
  for (int o = 0; o < 8; ++o) acc[o] = 0.f;
  for (int k = tid; k < 512; k += 256) {
    float h = fmaxf(c0 * w1[k] + c1 * w1[512 + k] + b1[k], 0.f);
#pragma unroll
    for (int o = 0; o < 8; ++o) acc[o] += h * w2[k * 8 + o];
  }
  __shared__ float part[4][8];
  int wave = tid >> 6;
#pragma unroll
  for (int o = 0; o < 8; ++o) {
    float v = acc[o];
    v += __shfl_xor(v, 1, 64);  v += __shfl_xor(v, 2, 64);
    v += __shfl_xor(v, 4, 64);  v += __shfl_xor(v, 8, 64);
    v += __shfl_xor(v, 16, 64); v += __shfl_xor(v, 32, 64);
    acc[o] = v;
  }
  if ((tid & 63) == 0)
#pragma unroll
    for (int o = 0; o < 8; ++o) part[wave][o] = acc[o];
  __syncthreads();
  if (tid < 8)
    table[row * 8 + tid] = part[0][tid] + part[1][tid] + part[2][tid] + part[3][tid];
}

// ---------------- k2: bias grid, permuted [h][tb][lane][r*4+nt] ----------------
__global__ void k_biasfill(const float* __restrict__ table, float* __restrict__ bias2) {
  int p = blockIdx.x * 256 + threadIdx.x;   // 32768 total
  int h = p >> 12, tb = (p >> 10) & 3, lane = (p >> 4) & 63, u = p & 15;
  int r = u >> 2, nt = u & 3, g = lane >> 4, li = lane & 15;
  int t = tb * 16 + g * 4 + r, s = nt * 16 + li;
  int idx = ((t >> 3) - (s >> 3) + 7) * 15 + ((t & 7) - (s & 7) + 7);
  float v = table[idx * 8 + h];
  bias2[p] = 16.0f / (1.0f + __expf(-v));
}

// -------- one QKV pass: C[64 x 192] slice, wave=(mt, nh); dual accumulators --------
template<int PASS>
__device__ inline void qkv_pass(const u16* __restrict__ R0, u16* __restrict__ R1,
                                const u16* __restrict__ wq, const float* __restrict__ qkvb,
                                int mt, int nh, int g, int li) {
  bf16x8 af[6];
#pragma unroll
  for (int ks = 0; ks < 6; ++ks)
    af[ks] = *(const bf16x8*)&R0[(mt * 16 + li) * 200 + ks * 32 + g * 8];
#pragma unroll
  for (int it = 0; it < 6; ++it) {
    int j = nh * 96 + it * 16 + li;                 // 0..191 (col within this pass)
    const u16* wr = wq + (PASS * 192 + j) * 192 + g * 8;
    f32x4 a0 = {0.f, 0.f, 0.f, 0.f}, a1 = a0;
#pragma unroll
    for (int ks = 0; ks < 3; ++ks) {
      bf16x8 b0 = *(const bf16x8*)(wr + ks * 32);
      bf16x8 b1 = *(const bf16x8*)(wr + (ks + 3) * 32);
      a0 = __builtin_amdgcn_mfma_f32_16x16x32_bf16(af[ks], b0, a0, 0, 0, 0);
      a1 = __builtin_amdgcn_mfma_f32_16x16x32_bf16(af[ks + 3], b1, a1, 0, 0, 0);
    }
    float cb = qkvb[PASS * 192 + j];
    float r0 = a0[0] + a1[0] + cb, r1 = a0[1] + a1[1] + cb;
    float r2 = a0[2] + a1[2] + cb, r3 = a0[3] + a1[3] + cb;
    if (PASS < 2) {                                 // q/k: [t][c], stride 200
      int rb = (mt * 16 + g * 4) * 200 + j;
      R1[rb] = f2bf(r0); R1[rb + 200] = f2bf(r1);
      R1[rb + 400] = f2bf(r2); R1[rb + 600] = f2bf(r3);
    } else {                                        // v: v^T [192][72], packed b64
      uint2 pk;
      pk.x = f2bf(r0) | ((unsigned)f2bf(r1) << 16);
      pk.y = f2bf(r2) | ((unsigned)f2bf(r3) << 16);
      *(uint2*)&R1[j * 72 + mt * 16 + g * 4] = pk;
    }
  }
}

// ---------------- main fused kernel: 1 window/block, 8 waves, 2 blocks/CU ----------------
__global__ __launch_bounds__(512, 4)
void k_main(const float* __restrict__ x,
            const float* __restrict__ ls, const float* __restrict__ proj_b,
            const u16* __restrict__ wq, const u16* __restrict__ wp,
            const float* __restrict__ qkvb, const float* __restrict__ bias2,
            float* __restrict__ out) {
  __shared__ u16 smem[37888];                 // 75,776 B -> 2 blocks/CU
  u16* R0 = smem;                             // [64][200]: x, later ao
  u16* R1 = smem + 12800;                     // q/k staging [64][200]; later v^T [192][72]
  u16* Pl = smem + 26624;                     // 8 x [16][72] per-wave P bounce
  float* invq = (float*)(smem + 35840);       // [8][64] (logit scale folded)
  float* invk = invq + 512;                   // [8][64]
  float* obuf = (float*)(smem + 12800);       // [64][196] fp32, overlays R1+Pl+inv (P5+)

  int tid  = threadIdx.x;
  int wave = tid >> 6, lane = tid & 63, g = lane >> 4, li = lane & 15;
  int mt = wave & 3, nh = wave >> 2;
  int bid = blockIdx.x;
  int b = bid >> 10, wy = (bid >> 5) & 31, wx = bid & 31;
  const float* xb = x + (size_t)b * C_ * HW_;
  int base = (wy * 8) * 256 + wx * 8;
  bf16x8 z8 = {0, 0, 0, 0, 0, 0, 0, 0};

  // ---- P1: stage x -> bf16 LDS ----
#pragma unroll
  for (int it = 0; it < 6; ++it) {
    int i4 = tid + it * 512;                  // 3072 tasks
    int c = i4 >> 4, rem = i4 & 15;
    int ty = rem >> 1, jj = (rem & 1) * 4;
    float4 v = *(const float4*)(xb + c * HW_ + base + ty * 256 + jj);
    int t = ty * 8 + jj;
    R0[(t + 0) * 200 + c] = f2bf(v.x);
    R0[(t + 1) * 200 + c] = f2bf(v.y);
    R0[(t + 2) * 200 + c] = f2bf(v.z);
    R0[(t + 3) * 200 + c] = f2bf(v.w);
  }
  __syncthreads();                            // B1

  bf16x8 qf[4], kf[4];

  // ---- P2a: q GEMM ----
  qkv_pass<0>(R0, R1, wq, qkvb, mt, nh, g, li);
  __syncthreads();                            // B2
  // ---- P3a: invq + hoist q-frags (wave = head) ----
  {
    const bf16x8* r8 = (const bf16x8*)&R1[lane * 200 + wave * 24];
    float ssq = 0.f;
#pragma unroll
    for (int ch = 0; ch < 3; ++ch) {
      bf16x8 v8 = r8[ch];
#pragma unroll
      for (int e = 0; e < 8; ++e) { float v = bf2f((u16)v8[e]); ssq += v * v; }
    }
    float inv = __builtin_amdgcn_rsqf(fmaxf(ssq, 1e-24f));
    inv *= __expf(fminf(ls[wave], 4.6051702f));
    invq[wave * 64 + lane] = inv;
#pragma unroll
    for (int tb = 0; tb < 4; ++tb)
      qf[tb] = (g < 3) ? *(const bf16x8*)&R1[(tb * 16 + li) * 200 + wave * 24 + g * 8] : z8;
  }
  __syncthreads();                            // B3

  // ---- P2b: k GEMM ----
  qkv_pass<1>(R0, R1, wq, qkvb, mt, nh, g, li);
  __syncthreads();                            // B4
  // ---- P3b: invk + hoist k-frags ----
  {
    const bf16x8* r8 = (const bf16x8*)&R1[lane * 200 + wave * 24];
    float ssq = 0.f;
#pragma unroll
    for (int ch = 0; ch < 3; ++ch) {
      bf16x8 v8 = r8[ch];
#pragma unroll
      for (int e = 0; e < 8; ++e) { float v = bf2f((u16)v8[e]); ssq += v * v; }
    }
    invk[wave * 64 + lane] = __builtin_amdgcn_rsqf(fmaxf(ssq, 1e-24f));
#pragma unroll
    for (int nt = 0; nt < 4; ++nt)
      kf[nt] = (g < 3) ? *(const bf16x8*)&R1[(nt * 16 + li) * 200 + wave * 24 + g * 8] : z8;
  }
  __syncthreads();                            // B5

  // ---- P2c: v GEMM -> v^T in R1 ----
  qkv_pass<2>(R0, R1, wq, qkvb, mt, nh, g, li);
  __syncthreads();                            // B6 (x in R0 now dead)

  // ---- P4: attention; wave = head; ao -> R0 ----
  {
    int h = wave;
    bf16x8 vf0[2], vf1[2];
#pragma unroll
    for (int ks = 0; ks < 2; ++ks) {
      vf0[ks] = *(const bf16x8*)&R1[(h * 24 + li) * 72 + ks * 32 + g * 8];
      vf1[ks] = (li < 8) ? *(const bf16x8*)&R1[(h * 24 + 16 + li) * 72 + ks * 32 + g * 8] : z8;
    }
    u16* Pw = Pl + wave * 1152;
#pragma unroll
    for (int tb = 0; tb < 4; ++tb) {
      const f32x4* bp = (const f32x4*)(bias2 + (((h * 4 + tb) * 64 + lane) << 4));
      f32x4 bx[4];
#pragma unroll
      for (int r = 0; r < 4; ++r) bx[r] = bp[r];
      f32x4 s4[4];
#pragma unroll
      for (int nt = 0; nt < 4; ++nt) {
        f32x4 z = {0.f, 0.f, 0.f, 0.f};
        s4[nt] = __builtin_amdgcn_mfma_f32_16x16x32_bf16(qf[tb], kf[nt], z, 0, 0, 0);
      }
      f32x4 iq = ((const f32x4*)(invq + h * 64 + tb * 16))[g];
#pragma unroll
      for (int nt = 0; nt < 4; ++nt) {
        float ik = invk[h * 64 + nt * 16 + li];
#pragma unroll
        for (int r = 0; r < 4; ++r)
          s4[nt][r] = s4[nt][r] * iq[r] * ik + bx[r][nt];
      }
#pragma unroll
      for (int r = 0; r < 4; ++r) {
        float m = fmaxf(fmaxf(s4[0][r], s4[1][r]), fmaxf(s4[2][r], s4[3][r]));
        m = fmaxf(m, __shfl_xor(m, 1, 64));
        m = fmaxf(m, __shfl_xor(m, 2, 64));
        m = fmaxf(m, __shfl_xor(m, 4, 64));
        m = fmaxf(m, __shfl_xor(m, 8, 64));
        float sum = 0.f;
#pragma unroll
        for (int nt = 0; nt < 4; ++nt) { float e = __expf(s4[nt][r] - m); s4[nt][r] = e; sum += e; }
        sum += __shfl_xor(sum, 1, 64);
        sum += __shfl_xor(sum, 2, 64);
        sum += __shfl_xor(sum, 4, 64);
        sum += __shfl_xor(sum, 8, 64);
        float is = __builtin_amdgcn_rcpf(sum);
#pragma unroll
        for (int nt = 0; nt < 4; ++nt)
          Pw[(g * 4 + r) * 72 + nt * 16 + li] = f2bf(s4[nt][r] * is);
      }
      // PV: O^T = V^T * P^T (same-wave LDS bounce)
      f32x4 o0 = {0.f, 0.f, 0.f, 0.f}, o1 = o0;
#pragma unroll
      for (int ks = 0; ks < 2; ++ks) {
        bf16x8 pf = *(const bf16x8*)&Pw[li * 72 + ks * 32 + g * 8];
        o0 = __builtin_amdgcn_mfma_f32_16x16x32_bf16(vf0[ks], pf, o0, 0, 0, 0);
        o1 = __builtin_amdgcn_mfma_f32_16x16x32_bf16(vf1[ks], pf, o1, 0, 0, 0);
      }
      int t = tb * 16 + li;
      {
        uint2 pk;
        pk.x = f2bf(o0[0]) | ((unsigned)f2bf(o0[1]) << 16);
        pk.y = f2bf(o0[2]) | ((unsigned)f2bf(o0[3]) << 16);
        *(uint2*)&R0[t * 200 + h * 24 + g * 4] = pk;
      }
      if (g < 2) {
        uint2 pk;
        pk.x = f2bf(o1[0]) | ((unsigned)f2bf(o1[1]) << 16);
        pk.y = f2bf(o1[2]) | ((unsigned)f2bf(o1[3]) << 16);
        *(uint2*)&R0[t * 200 + h * 24 + 16 + g * 4] = pk;
      }
    }
  }
  __syncthreads();                            // B7 (R1/Pl/inv dead -> obuf)

  // ---- P5: proj GEMM from ao (R0) -> obuf fp32 ----
  {
    bf16x8 af[6];
#pragma unroll
    for (int ks = 0; ks < 6; ++ks)
      af[ks] = *(const bf16x8*)&R0[(mt * 16 + li) * 200 + ks * 32 + g * 8];
#pragma unroll
    for (int it = 0; it < 6; ++it) {
      int j = nh * 96 + it * 16 + li;
      const u16* wr = wp + j * 192 + g * 8;
      f32x4 a0 = {0.f, 0.f, 0.f, 0.f}, a1 = a0;
#pragma unroll
      for (int ks = 0; ks < 3; ++ks) {
        bf16x8 b0 = *(const bf16x8*)(wr + ks * 32);
        bf16x8 b1 = *(const bf16x8*)(wr + (ks + 3) * 32);
        a0 = __builtin_amdgcn_mfma_f32_16x16x32_bf16(af[ks], b0, a0, 0, 0, 0);
        a1 = __builtin_amdgcn_mfma_f32_16x16x32_bf16(af[ks + 3], b1, a1, 0, 0, 0);
      }
      float pb = proj_b[j];
      int rb = (mt * 16 + g * 4) * 196 + j;
      obuf[rb]       = a0[0] + a1[0] + pb;
      obuf[rb + 196] = a0[1] + a1[1] + pb;
      obuf[rb + 392] = a0[2] + a1[2] + pb;
      obuf[rb + 588] = a0[3] + a1[3] + pb;
    }
  }
  __syncthreads();                            // B8

  // ---- P6: residual (x re-read, L3-resident) + coalesced store ----
  float* ob = out + (size_t)b * C_ * HW_;
#pragma unroll
  for (int it = 0; it < 6; ++it) {
    int i4 = tid + it * 512;
    int c = i4 >> 4, rem = i4 & 15;
    int ty = rem >> 1, jj = (rem & 1) * 4;
    int off = c * HW_ + base + ty * 256 + jj;
    float4 xv = *(const float4*)(xb + off);
    int t = ty * 8 + jj;
    float4 r;
    r.x = xv.x + obuf[(t + 0) * 196 + c];
    r.y = xv.y + obuf[(t + 1) * 196 + c];
    r.z = xv.z + obuf[(t + 2) * 196 + c];
    r.w = xv.w + obuf[(t + 3) * 196 + c];
    *(float4*)(ob + off) = r;
  }
}

// ---------------- launcher ----------------
extern "C" void kernel_launch(void* const* d_in, const int* in_sizes, int n_in,
                              void* d_out, int out_size, void* d_ws, size_t ws_size,
                              hipStream_t stream) {
  const float* x      = (const float*)d_in[0];
  const float* qkv_w  = (const float*)d_in[2];
  const float* q_bias = (const float*)d_in[3];
  const float* v_bias = (const float*)d_in[4];
  const float* ls     = (const float*)d_in[5];
  const float* w1     = (const float*)d_in[6];
  const float* b1     = (const float*)d_in[7];
  const float* w2     = (const float*)d_in[8];
  const float* proj_w = (const float*)d_in[9];
  const float* proj_b = (const float*)d_in[10];

  u16*   wq    = (u16*)d_ws;                               // 110592 bf16
  u16*   wpv   = wq + 110592;                              // 36864 bf16 -> byte 294912
  float* qkvb  = (float*)((char*)d_ws + 294912);           // 576 f32   -> 297216
  float* bias2 = (float*)((char*)d_ws + 297216);           // 32768 f32 -> 428288
  float* table = (float*)((char*)d_ws + 428288);           // 1800 f32
  float* out   = (float*)d_out;

  hipLaunchKernelGGL(k_convert, dim3(579), dim3(256), 0, stream,
                     qkv_w, proj_w, q_bias, v_bias, wq, wpv, qkvb);
  hipLaunchKernelGGL(k_table, dim3(225), dim3(256), 0, stream, w1, b1, w2, table);
  hipLaunchKernelGGL(k_biasfill, dim3(128), dim3(256), 0, stream, table, bias2);
  hipLaunchKernelGGL(k_main, dim3(NWIN), dim3(512), 0, stream,
                     x, ls, proj_b, wq, wpv, qkvb, bias2, out);
}